// Round 1
// baseline (3106.374 us; speedup 1.0000x reference)
//
#include <hip/hip_runtime.h>

#define LOG2E 1.4426950408889634f

// broadcast lane `srclane`'s value to all lanes via v_readlane (SGPR result)
__device__ __forceinline__ float rl(float v, int srclane) {
  return __int_as_float(__builtin_amdgcn_readlane(__float_as_int(v), srclane));
}

// quad broadcast via DPP quad_perm (VALU-latency cross-lane within groups of 4)
template<int CTL>
__device__ __forceinline__ float qb(float v) {
  return __int_as_float(__builtin_amdgcn_update_dpp(0, __float_as_int(v), CTL, 0xF, 0xF, true));
}

__device__ __forceinline__ float fast_rcp(float x)  { return __builtin_amdgcn_rcpf(x); }
__device__ __forceinline__ float fast_exp2(float x) { return __builtin_amdgcn_exp2f(x); }

__device__ __forceinline__ float sigf(float x) {
  return fast_rcp(1.0f + fast_exp2(-LOG2E * x));
}
__device__ __forceinline__ float tanhfast(float x) {
  return fmaf(fast_rcp(1.0f + fast_exp2(-2.0f * LOG2E * x)), 2.0f, -1.0f);
}

// One bidirectional-LSTM layer. grid = 256 blocks (b*2+dir), block = 128 (2 waves).
// Wave 1: producer — computes pre-scaled, pre-negated xW(t)+b into LDS ring.
// Wave 0: consumer — runs the recurrence, one step per loop iteration.
// Lane layout: j = lane>>2 (hidden 0..15), g = lane&3 (gate i,f,g,o); weight row r = g*16+j.
template<int IN, bool LAST>
__global__ __launch_bounds__(128) void bilstm_layer(
    const float* __restrict__ x,     // (B,T,IN)
    const float* __restrict__ Wih,   // (2,64,IN)
    const float* __restrict__ Whh,   // (2,64,16)
    const float* __restrict__ bias,  // (2,64)
    float* __restrict__ out)         // (B,T,32) or (B,256,32) if LAST
{
  constexpr int T = 2048;
  constexpr int C = 64;          // ring chunk (steps)
  constexpr int NCH = T / C;
  const int b    = blockIdx.x >> 1;
  const int dir  = blockIdx.x & 1;
  const int tid  = threadIdx.x;
  const int wave = tid >> 6;
  const int lane = tid & 63;
  const int g = lane & 3;
  const int j = lane >> 2;
  const int r = g * 16 + j;
  const float ksc = (g == 2) ? 2.0f * LOG2E : LOG2E;  // fold act scale into weights

  __shared__ float ring[2][C * 64];

  if (wave == 1) {
    // ---------------- producer ----------------
    float wih[IN];
    const float* wr = Wih + (size_t)(dir * 64 + r) * IN;
#pragma unroll
    for (int k = 0; k < IN; ++k) wih[k] = -ksc * wr[k];
    const float bneg = -ksc * bias[dir * 64 + r];
    const float* xb = x + (size_t)b * T * IN + lane;
    for (int chunk = 0; chunk <= NCH; ++chunk) {
      if (chunk < NCH) {
        float* buf = ring[chunk & 1];
        for (int s = 0; s < C; ++s) {
          const int tt = chunk * C + s;
          const int t  = dir ? (T - 1 - tt) : tt;
          const float xv = (lane < IN) ? xb[(size_t)t * IN] : 0.0f;
          float a0 = bneg, a1 = 0.0f;
#pragma unroll
          for (int k = 0; k + 1 < IN; k += 2) {
            a0 = fmaf(rl(xv, k),     wih[k],     a0);
            a1 = fmaf(rl(xv, k + 1), wih[k + 1], a1);
          }
          buf[s * 64 + lane] = a0 + a1;   // = -ksc*(Wih·x_t + b)
        }
      }
      __syncthreads();
    }
  } else {
    // ---------------- consumer (recurrence) ----------------
    float whh[16];
    const float* wr = Whh + (size_t)(dir * 64 + r) * 16;
#pragma unroll
    for (int k = 0; k < 16; ++k) whh[k] = -ksc * wr[k];
    const float amul = (g == 2) ? 2.0f : 1.0f;   // tanh = 2*sigmoid(2x)-1
    const float aadd = (g == 2) ? -1.0f : 0.0f;
    float c = 0.0f, h = 0.0f;
    float* opN = out + ((size_t)b * T)   * 32 + dir * 16 + j;
    float* opL = out + ((size_t)b * 256) * 32 + dir * 16 + j;
    __syncthreads();   // wait for producer's first chunk
    for (int chunk = 0; chunk < NCH; ++chunk) {
      const float* buf = ring[chunk & 1];
      for (int s = 0; s < C; ++s) {
        const int tt = chunk * C + s;
        const int t  = dir ? (T - 1 - tt) : tt;
        const float pre = buf[s * 64 + lane];          // ds_read, h-independent
        // 64x16 matvec: 4 independent FMA chains, h broadcast via readlane
        float a0 = 0.f, a1 = 0.f, a2 = 0.f, a3 = 0.f;
#pragma unroll
        for (int k = 0; k < 4; ++k) {
          a0 = fmaf(rl(h, 16 * k),      whh[4 * k],     a0);
          a1 = fmaf(rl(h, 16 * k + 4),  whh[4 * k + 1], a1);
          a2 = fmaf(rl(h, 16 * k + 8),  whh[4 * k + 2], a2);
          a3 = fmaf(rl(h, 16 * k + 12), whh[4 * k + 3], a3);
        }
        const float acc = ((a0 + a1) + (a2 + a3)) + pre;   // = -ksc * preact
        const float e   = fast_exp2(acc);
        const float sgm = fast_rcp(1.0f + e);              // sigmoid(ksc'*P)
        const float act = fmaf(sgm, amul, aadd);           // sigmoid or tanh
        const float ia = qb<0x00>(act);
        const float fa = qb<0x55>(act);
        const float ga = qb<0xAA>(act);
        const float oa = qb<0xFF>(act);
        c = fmaf(fa, c, ia * ga);
        const float e2 = fast_exp2(c * (-2.0f * LOG2E));
        const float tc = fmaf(fast_rcp(1.0f + e2), 2.0f, -1.0f);  // tanh(c)
        h = oa * tc;
        if (g == 0) {
          if (!LAST) {
            opN[(size_t)t * 32] = h;
          } else if ((t & 7) == 7) {
            opL[(size_t)(t >> 3) * 32] = h;
          }
        }
      }
      __syncthreads();
    }
  }
}

// Precompute layer-0 xW for the unidirectional stack: xw0[b][t][g] = ub0[g] + uWih0[g]·x
__global__ __launch_bounds__(256) void uni_xw0(
    const float* __restrict__ dsb,    // (B,256,32)
    const float* __restrict__ uWih0,  // (4,32)
    const float* __restrict__ ub,     // (4,4) — row 0 used
    float* __restrict__ xw0)          // (B,256,4)
{
  const int b = blockIdx.x;
  const int t = threadIdx.x;
  const float* xp = dsb + ((size_t)b * 256 + t) * 32;
  float xv[32];
#pragma unroll
  for (int k = 0; k < 32; k += 4) {
    const float4 v = *(const float4*)(xp + k);
    xv[k] = v.x; xv[k + 1] = v.y; xv[k + 2] = v.z; xv[k + 3] = v.w;
  }
  float4 o;
  float* po = &o.x;
#pragma unroll
  for (int gg = 0; gg < 4; ++gg) {
    float a0 = ub[gg], a1 = 0.f;
#pragma unroll
    for (int k = 0; k < 32; k += 2) {
      a0 = fmaf(uWih0[gg * 32 + k],     xv[k],     a0);
      a1 = fmaf(uWih0[gg * 32 + k + 1], xv[k + 1], a1);
    }
    po[gg] = a0 + a1;
  }
  *(float4*)(xw0 + ((size_t)b * 256 + t) * 4) = o;
}

// Fused 4-layer unidirectional stack (HU=1), step-synchronous across layers.
// lane = batch element. grid 2 x 64.
__global__ __launch_bounds__(64) void uni_stack(
    const float* __restrict__ xw0,   // (B,256,4) pre-biased layer-0 xW
    const float* __restrict__ uWih,  // (3,4,1)
    const float* __restrict__ uWhh,  // (4,4,1)
    const float* __restrict__ ub,    // (4,4)
    float* __restrict__ out)         // (B,256)
{
  const int b = blockIdx.x * 64 + threadIdx.x;
  float whh[4][4], wih[3][4], bs[3][4];
#pragma unroll
  for (int l = 0; l < 4; ++l)
#pragma unroll
    for (int gg = 0; gg < 4; ++gg) whh[l][gg] = uWhh[l * 4 + gg];
#pragma unroll
  for (int l = 0; l < 3; ++l)
#pragma unroll
    for (int gg = 0; gg < 4; ++gg) {
      wih[l][gg] = uWih[l * 4 + gg];
      bs[l][gg]  = ub[(l + 1) * 4 + gg];
    }
  float h[4] = {0, 0, 0, 0}, c[4] = {0, 0, 0, 0};
  const float4* xp = (const float4*)(xw0 + (size_t)b * 256 * 4);
  float* op = out + (size_t)b * 256;
  for (int t = 0; t < 256; ++t) {
    const float4 xw = xp[t];
    {
      const float i0 = sigf(fmaf(whh[0][0], h[0], xw.x));
      const float f0 = sigf(fmaf(whh[0][1], h[0], xw.y));
      const float g0 = tanhfast(fmaf(whh[0][2], h[0], xw.z));
      const float o0 = sigf(fmaf(whh[0][3], h[0], xw.w));
      c[0] = fmaf(f0, c[0], i0 * g0);
      h[0] = o0 * tanhfast(c[0]);
    }
#pragma unroll
    for (int l = 1; l < 4; ++l) {
      const float xin = h[l - 1];
      const float pi  = fmaf(whh[l][0], h[l], fmaf(wih[l - 1][0], xin, bs[l - 1][0]));
      const float pf  = fmaf(whh[l][1], h[l], fmaf(wih[l - 1][1], xin, bs[l - 1][1]));
      const float pg  = fmaf(whh[l][2], h[l], fmaf(wih[l - 1][2], xin, bs[l - 1][2]));
      const float po_ = fmaf(whh[l][3], h[l], fmaf(wih[l - 1][3], xin, bs[l - 1][3]));
      const float il = sigf(pi), fl = sigf(pf), gl = tanhfast(pg), ol = sigf(po_);
      c[l] = fmaf(fl, c[l], il * gl);
      h[l] = ol * tanhfast(c[l]);
    }
    op[t] = h[3];
  }
}

extern "C" void kernel_launch(void* const* d_in, const int* in_sizes, int n_in,
                              void* d_out, int out_size, void* d_ws, size_t ws_size,
                              hipStream_t stream)
{
  (void)in_sizes; (void)n_in; (void)out_size; (void)ws_size;
  const float* r_c_s = (const float*)d_in[0];
  const float* bWih0 = (const float*)d_in[1];
  const float* bWih  = (const float*)d_in[2];
  const float* bWhh  = (const float*)d_in[3];
  const float* bb    = (const float*)d_in[4];
  const float* uWih0 = (const float*)d_in[5];
  const float* uWih  = (const float*)d_in[6];
  const float* uWhh  = (const float*)d_in[7];
  const float* ub    = (const float*)d_in[8];
  float* outp = (float*)d_out;

  // workspace layout (floats): two (B,T,32) ping-pong, (B,256,32) downsample, (B,256,4) uni-xW
  float* x0  = (float*)d_ws;
  float* x1  = x0  + (size_t)128 * 2048 * 32;
  float* dsb = x1  + (size_t)128 * 2048 * 32;
  float* xw0 = dsb + (size_t)128 * 256 * 32;

  const dim3 grid(256), block(128);
  bilstm_layer<24, false><<<grid, block, 0, stream>>>(r_c_s, bWih0,               bWhh + 0,               bb + 0,          x0);
  bilstm_layer<32, false><<<grid, block, 0, stream>>>(x0,    bWih + 0 * 2*64*32,  bWhh + 1 * 2*64*16,     bb + 1 * 2*64,   x1);
  bilstm_layer<32, false><<<grid, block, 0, stream>>>(x1,    bWih + 1 * 2*64*32,  bWhh + 2 * 2*64*16,     bb + 2 * 2*64,   x0);
  bilstm_layer<32, true ><<<grid, block, 0, stream>>>(x0,    bWih + 2 * 2*64*32,  bWhh + 3 * 2*64*16,     bb + 3 * 2*64,   dsb);
  uni_xw0 <<<dim3(128), dim3(256), 0, stream>>>(dsb, uWih0, ub, xw0);
  uni_stack<<<dim3(2),   dim3(64),  0, stream>>>(xw0, uWih, uWhh, ub, outp);
}

// Round 2
// 1418.591 us; speedup vs baseline: 2.1898x; 2.1898x over previous
//
#include <hip/hip_runtime.h>

#define LOG2E 1.4426950408889634f

// broadcast lane `srclane`'s value to all lanes via v_readlane (SGPR result).
// srclane may be a wave-uniform dynamic value (SGPR lane select).
__device__ __forceinline__ float rl(float v, int srclane) {
  return __int_as_float(__builtin_amdgcn_readlane(__float_as_int(v), srclane));
}

// quad broadcast via DPP quad_perm (VALU-latency cross-lane within groups of 4)
template<int CTL>
__device__ __forceinline__ float qb(float v) {
  return __int_as_float(__builtin_amdgcn_update_dpp(0, __float_as_int(v), CTL, 0xF, 0xF, true));
}

__device__ __forceinline__ float fast_rcp(float x)  { return __builtin_amdgcn_rcpf(x); }
__device__ __forceinline__ float fast_exp2(float x) { return __builtin_amdgcn_exp2f(x); }

__device__ __forceinline__ float sigf(float x) {
  return fast_rcp(1.0f + fast_exp2(-LOG2E * x));
}
__device__ __forceinline__ float tanhfast(float x) {
  return fmaf(fast_rcp(1.0f + fast_exp2(-2.0f * LOG2E * x)), 2.0f, -1.0f);
}

// One bidirectional-LSTM layer. grid = 256 blocks (b*2+dir), block = 192 (3 waves).
// Wave 0: consumer — runs the recurrence, one step per iteration.
// Waves 1,2: producers — bulk-load a 64-step x chunk into registers (one row per
//   lane, 6-8 independent dwordx4 loads -> ONE memory latency per chunk instead of
//   one per step), then compute pre-scaled, pre-negated xW(t)+b into the LDS ring
//   via wave-uniform v_readlane row broadcasts. Waves 1/2 take even/odd steps.
// Lane layout: j = lane>>2 (hidden 0..15), g = lane&3 (gate i,f,g,o); row r = g*16+j.
template<int IN, bool LAST>
__global__ __launch_bounds__(192) void bilstm_layer(
    const float* __restrict__ x,     // (B,T,IN)
    const float* __restrict__ Wih,   // (2,64,IN)
    const float* __restrict__ Whh,   // (2,64,16)
    const float* __restrict__ bias,  // (2,64)
    float* __restrict__ out)         // (B,T,32) or (B,256,32) if LAST
{
  constexpr int T = 2048;
  constexpr int C = 64;          // ring chunk (steps)
  constexpr int NCH = T / C;
  constexpr int NV4 = IN / 4;    // float4 loads per row
  const int b    = blockIdx.x >> 1;
  const int dir  = blockIdx.x & 1;
  const int tid  = threadIdx.x;
  const int wave = tid >> 6;
  const int lane = tid & 63;
  const int g = lane & 3;
  const int j = lane >> 2;
  const int r = g * 16 + j;
  // fold activation arg scale into weights/bias: gate lanes get log2e, g-gate
  // gets 2*log2e (tanh = 2*sigmoid(2x)-1), all negated so e = exp2(acc) directly.
  const float ksc = (g == 2) ? 2.0f * LOG2E : LOG2E;

  __shared__ float ring[2][C * 64];

  if (wave >= 1) {
    // ---------------- producers ----------------
    const int pw = wave - 1;     // 0 or 1: even / odd steps
    float wih[IN];
    const float* wr = Wih + (size_t)(dir * 64 + r) * IN;
#pragma unroll
    for (int k = 0; k < IN; ++k) wih[k] = -ksc * wr[k];
    const float bneg = -ksc * bias[dir * 64 + r];
    const float* xb = x + (size_t)b * T * IN;
    for (int chunk = 0; chunk <= NCH; ++chunk) {
      if (chunk < NCH) {
        const int tt0  = chunk * C;
        const int tmin = dir ? (T - C - tt0) : tt0;   // chunk covers rows [tmin, tmin+C)
        const float* src = xb + (size_t)(tmin + lane) * IN;
        float4 xr[NV4];
#pragma unroll
        for (int v = 0; v < NV4; ++v) xr[v] = *(const float4*)(src + 4 * v);
        float* buf = ring[chunk & 1];
        for (int s = pw; s < C; s += 2) {
          const int row = dir ? (C - 1 - s) : s;      // lane holding x for this step
          float a0 = bneg, a1 = 0.0f;
#pragma unroll
          for (int v = 0; v < NV4; ++v) {
            const float x0 = rl(xr[v].x, row);
            const float x1 = rl(xr[v].y, row);
            const float x2 = rl(xr[v].z, row);
            const float x3 = rl(xr[v].w, row);
            a0 = fmaf(x0, wih[4 * v + 0], a0);
            a1 = fmaf(x1, wih[4 * v + 1], a1);
            a0 = fmaf(x2, wih[4 * v + 2], a0);
            a1 = fmaf(x3, wih[4 * v + 3], a1);
          }
          buf[s * 64 + lane] = a0 + a1;   // = -ksc*(Wih·x_t + b)
        }
      }
      __syncthreads();
    }
  } else {
    // ---------------- consumer (recurrence) ----------------
    float whh[16];
    const float* wr = Whh + (size_t)(dir * 64 + r) * 16;
#pragma unroll
    for (int k = 0; k < 16; ++k) whh[k] = -ksc * wr[k];
    // keep c scaled: ct = -2*log2e * c. Fold the extra -2*log2e into the g-gate
    // activation constants so the c-update needs no extra multiply before exp2.
    const float amul = (g == 2) ? -4.0f * LOG2E : 1.0f;
    const float aadd = (g == 2) ?  2.0f * LOG2E : 0.0f;
    float ct = 0.0f, h = 0.0f;
    float* opN = out + ((size_t)b * T)   * 32 + dir * 16 + j;
    float* opL = out + ((size_t)b * 256) * 32 + dir * 16 + j;
    __syncthreads();   // wait for producers' first chunk
    for (int chunk = 0; chunk < NCH; ++chunk) {
      const float* buf = ring[chunk & 1];
      float pre = buf[lane];                       // prefetch s=0
      for (int s = 0; s < C; ++s) {
        const float pre_n = buf[(((s + 1) & (C - 1)) * 64) + lane];  // prefetch next
        const int tt = chunk * C + s;
        const int t  = dir ? (T - 1 - tt) : tt;
        // 64x16 matvec: 4 independent FMA chains, h broadcast via readlane.
        // a0 seeded with pre (the -ksc*(xW+b) term) — ready early, saves an add.
        float a0 = pre, a1 = 0.f, a2 = 0.f, a3 = 0.f;
#pragma unroll
        for (int k = 0; k < 4; ++k) {
          a0 = fmaf(rl(h, 16 * k),      whh[4 * k],     a0);
          a1 = fmaf(rl(h, 16 * k + 4),  whh[4 * k + 1], a1);
          a2 = fmaf(rl(h, 16 * k + 8),  whh[4 * k + 2], a2);
          a3 = fmaf(rl(h, 16 * k + 12), whh[4 * k + 3], a3);
        }
        const float acc = (a0 + a1) + (a2 + a3);           // = -ksc * preact
        const float e   = fast_exp2(acc);
        const float sgm = fast_rcp(1.0f + e);              // sigmoid(ksc'*P)
        const float act = fmaf(sgm, amul, aadd);           // sigmoid / -2log2e*tanh
        const float ia = qb<0x00>(act);
        const float fa = qb<0x55>(act);
        const float ga = qb<0xAA>(act);                    // = -2log2e * g
        const float oa = qb<0xFF>(act);
        ct = fmaf(fa, ct, ia * ga);                        // ct = -2log2e * c
        const float e2 = fast_exp2(ct);
        const float tc = fmaf(fast_rcp(1.0f + e2), 2.0f, -1.0f);  // tanh(c), inf-safe
        h = oa * tc;
        if (g == 0) {
          if (!LAST) {
            opN[(size_t)t * 32] = h;
          } else if ((t & 7) == 7) {
            opL[(size_t)(t >> 3) * 32] = h;
          }
        }
        pre = pre_n;
      }
      __syncthreads();
    }
  }
}

// Precompute layer-0 xW for the unidirectional stack: xw0[b][t][g] = ub0[g] + uWih0[g]·x
__global__ __launch_bounds__(256) void uni_xw0(
    const float* __restrict__ dsb,    // (B,256,32)
    const float* __restrict__ uWih0,  // (4,32)
    const float* __restrict__ ub,     // (4,4) — row 0 used
    float* __restrict__ xw0)          // (B,256,4)
{
  const int b = blockIdx.x;
  const int t = threadIdx.x;
  const float* xp = dsb + ((size_t)b * 256 + t) * 32;
  float xv[32];
#pragma unroll
  for (int k = 0; k < 32; k += 4) {
    const float4 v = *(const float4*)(xp + k);
    xv[k] = v.x; xv[k + 1] = v.y; xv[k + 2] = v.z; xv[k + 3] = v.w;
  }
  float4 o;
  float* po = &o.x;
#pragma unroll
  for (int gg = 0; gg < 4; ++gg) {
    float a0 = ub[gg], a1 = 0.f;
#pragma unroll
    for (int k = 0; k < 32; k += 2) {
      a0 = fmaf(uWih0[gg * 32 + k],     xv[k],     a0);
      a1 = fmaf(uWih0[gg * 32 + k + 1], xv[k + 1], a1);
    }
    po[gg] = a0 + a1;
  }
  *(float4*)(xw0 + ((size_t)b * 256 + t) * 4) = o;
}

// Fused 4-layer unidirectional stack (HU=1), step-synchronous across layers.
// lane = batch element. grid 2 x 64.
__global__ __launch_bounds__(64) void uni_stack(
    const float* __restrict__ xw0,   // (B,256,4) pre-biased layer-0 xW
    const float* __restrict__ uWih,  // (3,4,1)
    const float* __restrict__ uWhh,  // (4,4,1)
    const float* __restrict__ ub,    // (4,4)
    float* __restrict__ out)         // (B,256)
{
  const int b = blockIdx.x * 64 + threadIdx.x;
  float whh[4][4], wih[3][4], bs[3][4];
#pragma unroll
  for (int l = 0; l < 4; ++l)
#pragma unroll
    for (int gg = 0; gg < 4; ++gg) whh[l][gg] = uWhh[l * 4 + gg];
#pragma unroll
  for (int l = 0; l < 3; ++l)
#pragma unroll
    for (int gg = 0; gg < 4; ++gg) {
      wih[l][gg] = uWih[l * 4 + gg];
      bs[l][gg]  = ub[(l + 1) * 4 + gg];
    }
  float h[4] = {0, 0, 0, 0}, c[4] = {0, 0, 0, 0};
  const float4* xp = (const float4*)(xw0 + (size_t)b * 256 * 4);
  float* op = out + (size_t)b * 256;
  for (int t = 0; t < 256; ++t) {
    const float4 xw = xp[t];
    {
      const float i0 = sigf(fmaf(whh[0][0], h[0], xw.x));
      const float f0 = sigf(fmaf(whh[0][1], h[0], xw.y));
      const float g0 = tanhfast(fmaf(whh[0][2], h[0], xw.z));
      const float o0 = sigf(fmaf(whh[0][3], h[0], xw.w));
      c[0] = fmaf(f0, c[0], i0 * g0);
      h[0] = o0 * tanhfast(c[0]);
    }
#pragma unroll
    for (int l = 1; l < 4; ++l) {
      const float xin = h[l - 1];
      const float pi  = fmaf(whh[l][0], h[l], fmaf(wih[l - 1][0], xin, bs[l - 1][0]));
      const float pf  = fmaf(whh[l][1], h[l], fmaf(wih[l - 1][1], xin, bs[l - 1][1]));
      const float pg  = fmaf(whh[l][2], h[l], fmaf(wih[l - 1][2], xin, bs[l - 1][2]));
      const float po_ = fmaf(whh[l][3], h[l], fmaf(wih[l - 1][3], xin, bs[l - 1][3]));
      const float il = sigf(pi), fl = sigf(pf), gl = tanhfast(pg), ol = sigf(po_);
      c[l] = fmaf(fl, c[l], il * gl);
      h[l] = ol * tanhfast(c[l]);
    }
    op[t] = h[3];
  }
}

extern "C" void kernel_launch(void* const* d_in, const int* in_sizes, int n_in,
                              void* d_out, int out_size, void* d_ws, size_t ws_size,
                              hipStream_t stream)
{
  (void)in_sizes; (void)n_in; (void)out_size; (void)ws_size;
  const float* r_c_s = (const float*)d_in[0];
  const float* bWih0 = (const float*)d_in[1];
  const float* bWih  = (const float*)d_in[2];
  const float* bWhh  = (const float*)d_in[3];
  const float* bb    = (const float*)d_in[4];
  const float* uWih0 = (const float*)d_in[5];
  const float* uWih  = (const float*)d_in[6];
  const float* uWhh  = (const float*)d_in[7];
  const float* ub    = (const float*)d_in[8];
  float* outp = (float*)d_out;

  // workspace layout (floats): two (B,T,32) ping-pong, (B,256,32) downsample, (B,256,4) uni-xW
  float* x0  = (float*)d_ws;
  float* x1  = x0  + (size_t)128 * 2048 * 32;
  float* dsb = x1  + (size_t)128 * 2048 * 32;
  float* xw0 = dsb + (size_t)128 * 256 * 32;

  const dim3 grid(256), block(192);
  bilstm_layer<24, false><<<grid, block, 0, stream>>>(r_c_s, bWih0,               bWhh + 0,               bb + 0,          x0);
  bilstm_layer<32, false><<<grid, block, 0, stream>>>(x0,    bWih + 0 * 2*64*32,  bWhh + 1 * 2*64*16,     bb + 1 * 2*64,   x1);
  bilstm_layer<32, false><<<grid, block, 0, stream>>>(x1,    bWih + 1 * 2*64*32,  bWhh + 2 * 2*64*16,     bb + 2 * 2*64,   x0);
  bilstm_layer<32, true ><<<grid, block, 0, stream>>>(x0,    bWih + 2 * 2*64*32,  bWhh + 3 * 2*64*16,     bb + 3 * 2*64,   dsb);
  uni_xw0 <<<dim3(128), dim3(256), 0, stream>>>(dsb, uWih0, ub, xw0);
  uni_stack<<<dim3(2),   dim3(64),  0, stream>>>(xw0, uWih, uWhh, ub, outp);
}